// Round 10
// baseline (185.702 us; speedup 1.0000x reference)
//
#include <hip/hip_runtime.h>
#include <hip/hip_fp16.h>
#include <math.h>

// Problem constants (fixed by the reference)
#define BN_NODES 16384     // B*N
#define DIM 128            // D
#define HID 256            // H
#define TK 2048            // distance-table knots
#define TRANGE 32.0f
#define TSTEP (TRANGE / (float)TK)   // 1/64
#define TINV  ((float)TK / TRANGE)   // 64
#define LN_EPS 1e-5f
#define EPB 4096           // edges per block in binA
#define NBINS 1024         // 16-node bins
#define CAPB 768           // staging capacity per bin (mean 512, +11 sigma)

typedef _Float16 f16x8 __attribute__((ext_vector_type(8)));
typedef __attribute__((ext_vector_type(4))) float f32x4;
typedef __attribute__((ext_vector_type(8))) unsigned short ushort8v;

__device__ __forceinline__ unsigned short f2h(float f) {
    _Float16 h = (_Float16)f;          // v_cvt_f16_f32, RNE
    return *(unsigned short*)&h;
}
__device__ __forceinline__ __half2 u2h2(unsigned int u) {
    union { unsigned int u; __half2 h; } c; c.u = u; return c.h;
}

// per-edge message accumulate: 1 dword xh gather + 1 dwordx2 pair-table
// gather + 2 packed hfma2. e = (c | k<<16, frac2).
__device__ __forceinline__ void edge_acc(uint2 e, int dd,
        const unsigned short* __restrict__ xh,
        const unsigned short* __restrict__ Tb2, __half2& acch) {
    int c = (int)(e.x & 0xffffu);
    int k = (int)(e.x >> 16);
    unsigned int hx = *(const unsigned int*)&xh[c * DIM + dd];
    uint2 tb = *(const uint2*)&Tb2[(k << 8) + dd * 2];
    __half2 filt = __hfma2(u2h2(tb.y), u2h2(e.y), u2h2(tb.x));
    acch = __hfma2(u2h2(hx), filt, acch);
}

// tail: 4-edge unrolled single-node gather (R9-proven), fp32 flush per window
__device__ __forceinline__ void node_tail(const uint2* lrec, int from, int to, int dd,
        const unsigned short* __restrict__ xh,
        const unsigned short* __restrict__ Tb2, float& a0, float& a1) {
    int i = from;
    for (; i + 4 <= to; i += 4) {
        __half2 acch = __float2half2_rn(0.f);
        uint2 e0 = lrec[i], e1 = lrec[i + 1], e2 = lrec[i + 2], e3 = lrec[i + 3];
        edge_acc(e0, dd, xh, Tb2, acch);
        edge_acc(e1, dd, xh, Tb2, acch);
        edge_acc(e2, dd, xh, Tb2, acch);
        edge_acc(e3, dd, xh, Tb2, acch);
        a0 += __low2float(acch);
        a1 += __high2float(acch);
    }
    __half2 acch = __float2half2_rn(0.f);
    for (; i < to; ++i) edge_acc(lrec[i], dd, xh, Tb2, acch);
    a0 += __low2float(acch);
    a1 += __high2float(acch);
}

// ---------------------------------------------------------------------------
// K1 "prep": blocks 0..255 build interleaved fp16 filter table
//   Tb2[k][pair p] = (A_{2p}, A_{2p+1}, D_{2p}, D_{2p+1}), A=T[k], D=T[k+1]-T[k]
// 256..319 transpose W3 -> w3t[n][k] fp16; 320..351 W4 -> w4t[n][k];
// 352..1375 h -> xh fp16; 1376..1376+hb-1 histogram; last block: cursor init.
__global__ __launch_bounds__(256) void prep_kernel(
        const float* __restrict__ W1, const float* __restrict__ b1,
        const float* __restrict__ W2, const float* __restrict__ b2,
        const float* __restrict__ W3, const float* __restrict__ W4,
        const float* __restrict__ h, const int* __restrict__ ei,
        unsigned short* __restrict__ Tb2, unsigned short* __restrict__ w3t,
        unsigned short* __restrict__ w4t, unsigned short* __restrict__ xh,
        int* __restrict__ counts, int* __restrict__ bin_cursor, int nE) {
    __shared__ float smem[9 * 256 + 9 * 128];   // 13.5 KB, role-dependent
    int bid = blockIdx.x, t = threadIdx.x;
    int hb = (nE + 255) >> 8;
    if (bid < 256) {
        float* a    = smem;            // [9][256]  (knots k0..k0+8 incl. boundary)
        float* part = smem + 9 * 256;  // [9][128]
        int k0 = bid * 8;
        float w1 = W1[t], bb = b1[t];
#pragma unroll
        for (int k = 0; k < 9; ++k) {
            float dist = (float)(k0 + k) * TSTEP;
            float z = dist * w1 + bb;
            a[k * 256 + t] = z / (1.0f + expf(-z));
        }
        __syncthreads();
        int hg = t >> 7, d = t & 127;
        float acc[9] = {0.f,0.f,0.f,0.f,0.f,0.f,0.f,0.f,0.f};
        for (int hh = 0; hh < 128; ++hh) {
            int hidx = hg * 128 + hh;
            float w = W2[hidx * DIM + d];
#pragma unroll
            for (int k = 0; k < 9; ++k) acc[k] += a[k * 256 + hidx] * w;
        }
        if (hg == 1) {
#pragma unroll
            for (int k = 0; k < 9; ++k) part[k * 128 + d] = acc[k];
        }
        __syncthreads();
        if (hg == 0) {
            float bd = b2[d];
            float v[9];
#pragma unroll
            for (int k = 0; k < 9; ++k) v[k] = acc[k] + part[k * 128 + d] + bd;
#pragma unroll
            for (int k = 0; k < 8; ++k) {
                unsigned int base = (unsigned int)(k0 + k) * 256u + (unsigned int)((d >> 1) * 4 + (d & 1));
                Tb2[base]     = f2h(v[k]);              // value
                Tb2[base + 2] = f2h(v[k + 1] - v[k]);   // delta
            }
        }
    } else if (bid < 320) {
        float* s = smem;   // [32][33]
        int tid = bid - 256, tr = tid >> 3, tc = tid & 7;
        int lr = t >> 5, lc = t & 31;
#pragma unroll
        for (int rep = 0; rep < 4; ++rep) {
            int k = tr * 32 + rep * 8 + lr, n = tc * 32 + lc;
            s[lc * 33 + rep * 8 + lr] = W3[k * 256 + n];
        }
        __syncthreads();
#pragma unroll
        for (int rep = 0; rep < 4; ++rep) {
            int n = tc * 32 + rep * 8 + lr, k = tr * 32 + lc;
            w3t[n * 256 + k] = f2h(s[(rep * 8 + lr) * 33 + lc]);
        }
    } else if (bid < 352) {
        float* s = smem;
        int tid = bid - 320, tr = tid >> 2, tc = tid & 3;
        int lr = t >> 5, lc = t & 31;
#pragma unroll
        for (int rep = 0; rep < 4; ++rep) {
            int k = tr * 32 + rep * 8 + lr, n = tc * 32 + lc;
            s[lc * 33 + rep * 8 + lr] = W4[k * 128 + n];
        }
        __syncthreads();
#pragma unroll
        for (int rep = 0; rep < 4; ++rep) {
            int n = tc * 32 + rep * 8 + lr, k = tr * 32 + lc;
            w4t[n * 256 + k] = f2h(s[(rep * 8 + lr) * 33 + lc]);
        }
    } else if (bid < 1376) {
        int i0 = (bid - 352) * 2048 + t * 8;
        float4 v0 = *(const float4*)&h[i0];
        float4 v1 = *(const float4*)&h[i0 + 4];
        ushort8v o;
        o[0] = f2h(v0.x); o[1] = f2h(v0.y); o[2] = f2h(v0.z); o[3] = f2h(v0.w);
        o[4] = f2h(v1.x); o[5] = f2h(v1.y); o[6] = f2h(v1.z); o[7] = f2h(v1.w);
        *(ushort8v*)&xh[i0] = o;
    } else if (bid < 1376 + hb) {
        int e = (bid - 1376) * 256 + t;
        if (e < nE) atomicAdd(&counts[ei[e]], 1);
    } else {
        for (int i = t; i < NBINS; i += 256) bin_cursor[i] = i * CAPB;
    }
}

// ---------------------------------------------------------------------------
// K2: bin scatter + edge precompute. 512 threads; LDS counting-sort 4096-edge
// chunks into 1024 bins (bin = row>>4); at write-out compute dist -> knot k
// and fp16 frac, emit uint2 (r<<16|c, k<<16|frac) into the bin's fixed
// staging region [bin*CAPB, ...). Bursty per-bin writes avoid the 13x write
// amplification of random 4B scatter across non-coherent XCD L2s.
__global__ __launch_bounds__(512) void binA_kernel(
        const int* __restrict__ ei, const float* __restrict__ x,
        int* __restrict__ bin_cursor, uint2* __restrict__ staging, int nE) {
    __shared__ int cnt[NBINS];
    __shared__ int pre[NBINS];
    __shared__ int gbase[NBINS];
    __shared__ int sc[512];
    __shared__ unsigned int rec[EPB];   // 16 KB
    int t = threadIdx.x;
    int e0 = blockIdx.x * EPB;
    int m = min(EPB, nE - e0);
    cnt[t] = 0; cnt[t + 512] = 0;
    __syncthreads();
    unsigned int code[8];
    int rk[8], bn[8];
#pragma unroll
    for (int j = 0; j < 8; ++j) {
        int idx = j * 512 + t;
        rk[j] = -1; bn[j] = 0; code[j] = 0;
        if (idx < m) {
            int e = e0 + idx;
            int r = ei[e], c = ei[nE + e];
            code[j] = ((unsigned int)r << 16) | (unsigned int)c;
            bn[j] = r >> 4;
            rk[j] = atomicAdd(&cnt[bn[j]], 1);
        }
    }
    __syncthreads();
    int c0 = cnt[2 * t], c1 = cnt[2 * t + 1];
    int s2 = c0 + c1;
    sc[t] = s2;
    __syncthreads();
    for (int off = 1; off < 512; off <<= 1) {
        int v = (t >= off) ? sc[t - off] : 0;
        __syncthreads();
        sc[t] += v;
        __syncthreads();
    }
    int excl = sc[t] - s2;
    pre[2 * t]     = excl;
    pre[2 * t + 1] = excl + c0;
    gbase[2 * t]     = atomicAdd(&bin_cursor[2 * t], c0);
    gbase[2 * t + 1] = atomicAdd(&bin_cursor[2 * t + 1], c1);
    __syncthreads();
#pragma unroll
    for (int j = 0; j < 8; ++j)
        if (rk[j] >= 0) rec[pre[bn[j]] + rk[j]] = code[j];
    __syncthreads();
    for (int i = t; i < m; i += 512) {
        unsigned int cd = rec[i];
        int b = (int)(cd >> 20);            // row >> 4
        int r = (int)(cd >> 16);
        int c = (int)(cd & 0xffffu);
        float dx = x[r * 3 + 0] - x[c * 3 + 0];
        float dy = x[r * 3 + 1] - x[c * 3 + 1];
        float dz = x[r * 3 + 2] - x[c * 3 + 2];
        float u = sqrtf(dx * dx + dy * dy + dz * dz) * TINV;
        int k = min((int)u, TK - 2);
        float frac = u - (float)k;
        uint2 o;
        o.x = cd;
        o.y = ((unsigned int)k << 16) | (unsigned int)f2h(frac);
        int idx = gbase[b] + (i - pre[b]);
        if (idx < (b + 1) * CAPB) staging[idx] = o;   // 11-sigma guard
    }
}

// ---------------------------------------------------------------------------
// K3 "mega" v2: 1024 blocks x 512 threads, 16 nodes/block -> 4 blocks/CU
// x 8 waves = 32 waves/CU (R9 was capped at 16: 1 block/CU), and 4
// independent blocks per CU let GEMM of one overlap gather of another.
// Phase 2: wave owns 2 nodes, bulk loop interleaves them 4-edges-each ->
// 16 gathers in flight across 2 independent accumulator chains.
__global__ __launch_bounds__(512, 8) void mega_kernel(
        const uint2* __restrict__ staging, const int* __restrict__ counts,
        const unsigned short* __restrict__ Tb2, const unsigned short* __restrict__ xh,
        const unsigned short* __restrict__ w3t, const float* __restrict__ b3,
        const float* __restrict__ gamma, const float* __restrict__ beta,
        const unsigned short* __restrict__ w4t, const float* __restrict__ b4,
        float* __restrict__ out) {
    __shared__ uint2 lrec[CAPB];                            // 6 KB
    __shared__ int pref[17];
    __shared__ int cur[16];
    __shared__ __align__(16) unsigned short aggh[16][136];  // 4.25 KB
    __shared__ __align__(16) unsigned short a_lds[16][264]; // 8.25 KB
    __shared__ float part_s[8][16], part_q[8][16];          // 1 KB
    __shared__ float tot_mu[16], tot_rs[16];

    int t = threadIdx.x;
    int bin = blockIdx.x;
    int n0 = bin * 16;

    // ---- phase 0: per-node exclusive prefix within bin (16 lanes)
    if (t < 16) {
        int c = counts[n0 + t];
        int s = c;
#pragma unroll
        for (int off = 1; off < 16; off <<= 1) {
            int v = __shfl_up(s, off, 16);
            if (t >= off) s += v;
        }
        pref[t + 1] = s;
        cur[t] = s - c;
        if (t == 0) pref[0] = 0;
    }
    __syncthreads();
    int total = min(pref[16], CAPB);
    long base = (long)bin * CAPB;

    // ---- phase 1: staging -> LDS records in CSR order
    for (int i = t; i < total; i += 512) {
        uint2 sr = staging[base + i];
        int r6 = ((int)(sr.x >> 16)) & 15;
        int pos = atomicAdd(&cur[r6], 1);
        uint2 o;
        o.x = (sr.x & 0xffffu) | (sr.y & 0xffff0000u);   // c | k<<16
        o.y = (sr.y & 0xffffu) * 0x10001u;               // frac2 (both halves)
        lrec[pos] = o;
    }
    __syncthreads();

    int wid = t >> 6, lane = t & 63, dd = lane * 2;

    // ---- phase 2: wave wid owns nodes wid*2, wid*2+1 (interleaved bulk)
    {
        int j0 = wid * 2, j1 = j0 + 1;
        int off0 = pref[j0], len0 = pref[j0 + 1] - off0;
        int off1 = pref[j1], len1 = pref[j1 + 1] - off1;
        float a0x = 0.f, a0y = 0.f, a1x = 0.f, a1y = 0.f;
        int minl = min(len0, len1);
        int i = 0;
        for (; i + 4 <= minl; i += 4) {
            uint2 ea0 = lrec[off0 + i],     eb0 = lrec[off1 + i];
            uint2 ea1 = lrec[off0 + i + 1], eb1 = lrec[off1 + i + 1];
            uint2 ea2 = lrec[off0 + i + 2], eb2 = lrec[off1 + i + 2];
            uint2 ea3 = lrec[off0 + i + 3], eb3 = lrec[off1 + i + 3];
            __half2 acc0 = __float2half2_rn(0.f);
            __half2 acc1 = __float2half2_rn(0.f);
            edge_acc(ea0, dd, xh, Tb2, acc0); edge_acc(eb0, dd, xh, Tb2, acc1);
            edge_acc(ea1, dd, xh, Tb2, acc0); edge_acc(eb1, dd, xh, Tb2, acc1);
            edge_acc(ea2, dd, xh, Tb2, acc0); edge_acc(eb2, dd, xh, Tb2, acc1);
            edge_acc(ea3, dd, xh, Tb2, acc0); edge_acc(eb3, dd, xh, Tb2, acc1);
            a0x += __low2float(acc0); a0y += __high2float(acc0);
            a1x += __low2float(acc1); a1y += __high2float(acc1);
        }
        node_tail(lrec, off0 + i, off0 + len0, dd, xh, Tb2, a0x, a0y);
        node_tail(lrec, off1 + i, off1 + len1, dd, xh, Tb2, a1x, a1y);
        float inv0 = 1.0f / (float)max(len0, 1);
        float inv1 = 1.0f / (float)max(len1, 1);
        unsigned int p0 = (unsigned int)f2h(a0x * inv0) | ((unsigned int)f2h(a0y * inv0) << 16);
        unsigned int p1 = (unsigned int)f2h(a1x * inv1) | ((unsigned int)f2h(a1y * inv1) << 16);
        *(unsigned int*)&aggh[j0][dd] = p0;
        *(unsigned int*)&aggh[j1][dd] = p1;
    }
    __syncthreads();

    // ---- phase 3: GEMM1: U[16,256] = [xh | aggh] @ W3; wave owns 32 cols
    int wv = wid, q = lane >> 4, l15 = lane & 15;
    f32x4 acc[2];
    acc[0] = (f32x4){0.f, 0.f, 0.f, 0.f};
    acc[1] = (f32x4){0.f, 0.f, 0.f, 0.f};
    for (int kc = 0; kc < 8; ++kc) {
        f16x8 a;
        if (kc < 4) a = *(const f16x8*)&xh[(n0 + l15) * DIM + kc * 32 + q * 8];
        else        a = *(const f16x8*)&aggh[l15][(kc - 4) * 32 + q * 8];
#pragma unroll
        for (int nt = 0; nt < 2; ++nt) {
            f16x8 b = *(const f16x8*)&w3t[(wv * 32 + nt * 16 + l15) * 256 + kc * 32 + q * 8];
            acc[nt] = __builtin_amdgcn_mfma_f32_16x16x32_f16(a, b, acc[nt], 0, 0, 0);
        }
    }

    // bias + LN stats (intra-16-lane shfl, then cross-wave LDS sum)
    float b3v[2], gv[2], bvv[2];
#pragma unroll
    for (int nt = 0; nt < 2; ++nt) {
        int col = wv * 32 + nt * 16 + l15;
        b3v[nt] = b3[col]; gv[nt] = gamma[col]; bvv[nt] = beta[col];
    }
    {
        float s_[4], q_[4];
#pragma unroll
        for (int reg = 0; reg < 4; ++reg) {
            float su = 0.f, sq = 0.f;
#pragma unroll
            for (int nt = 0; nt < 2; ++nt) {
                float v = acc[nt][reg] + b3v[nt];
                acc[nt][reg] = v;
                su += v; sq += v * v;
            }
            s_[reg] = su; q_[reg] = sq;
        }
#pragma unroll
        for (int off = 1; off < 16; off <<= 1) {
#pragma unroll
            for (int reg = 0; reg < 4; ++reg) {
                s_[reg] += __shfl_xor(s_[reg], off, 64);
                q_[reg] += __shfl_xor(q_[reg], off, 64);
            }
        }
        if (l15 == 0) {
#pragma unroll
            for (int reg = 0; reg < 4; ++reg) {
                int r = q * 4 + reg;
                part_s[wv][r] = s_[reg];
                part_q[wv][r] = q_[reg];
            }
        }
    }
    __syncthreads();
    if (t < 16) {
        float st = 0.f, qt = 0.f;
#pragma unroll
        for (int w = 0; w < 8; ++w) { st += part_s[w][t]; qt += part_q[w][t]; }
        float mu = st * (1.0f / 256.0f);
        float var = qt * (1.0f / 256.0f) - mu * mu;
        tot_mu[t] = mu;
        tot_rs[t] = rsqrtf(var + LN_EPS);
    }
    __syncthreads();

    // LN + SiLU -> fp16 act in LDS (A-operand layout [m][k])
#pragma unroll
    for (int reg = 0; reg < 4; ++reg) {
        int r = q * 4 + reg;
        float mu = tot_mu[r], rs = tot_rs[r];
#pragma unroll
        for (int nt = 0; nt < 2; ++nt) {
            float un = (acc[nt][reg] - mu) * rs * gv[nt] + bvv[nt];
            float act = un / (1.0f + expf(-un));
            a_lds[r][wv * 32 + nt * 16 + l15] = f2h(act);
        }
    }
    __syncthreads();

    // GEMM2: out[16,128] = act @ W4; wave wv owns cols wv*16..+15
    f32x4 acc2 = (f32x4){0.f, 0.f, 0.f, 0.f};
    int col2 = wv * 16 + l15;
    for (int kc = 0; kc < 8; ++kc) {
        f16x8 a = *(const f16x8*)&a_lds[l15][kc * 32 + q * 8];
        f16x8 b = *(const f16x8*)&w4t[col2 * 256 + kc * 32 + q * 8];
        acc2 = __builtin_amdgcn_mfma_f32_16x16x32_f16(a, b, acc2, 0, 0, 0);
    }
    float b4v = b4[col2];
#pragma unroll
    for (int reg = 0; reg < 4; ++reg) {
        int node = n0 + q * 4 + reg;
        out[node * DIM + col2] = acc2[reg] + b4v;
    }
}

// ---------------------------------------------------------------------------
extern "C" void kernel_launch(void* const* d_in, const int* in_sizes, int n_in,
                              void* d_out, int out_size, void* d_ws, size_t ws_size,
                              hipStream_t stream) {
    const float* x     = (const float*)d_in[0];
    const float* h     = (const float*)d_in[1];
    const int*   ei    = (const int*)d_in[2];
    const float* W1    = (const float*)d_in[4];
    const float* b1    = (const float*)d_in[5];
    const float* W2    = (const float*)d_in[6];
    const float* b2    = (const float*)d_in[7];
    const float* W3    = (const float*)d_in[8];
    const float* b3    = (const float*)d_in[9];
    const float* gamma = (const float*)d_in[10];
    const float* beta  = (const float*)d_in[11];
    const float* W4    = (const float*)d_in[12];
    const float* b4    = (const float*)d_in[13];
    float* out = (float*)d_out;
    int nE = in_sizes[2] / 2;

    char* ws = (char*)d_ws;
    unsigned short* Tb2  = (unsigned short*)ws; ws += (size_t)TK * 256 * 2;       // 1 MB (pair table)
    unsigned short* w3t  = (unsigned short*)ws; ws += (size_t)HID * HID * 2;      // 128 KB
    unsigned short* w4t  = (unsigned short*)ws; ws += (size_t)DIM * HID * 2;      // 64 KB
    unsigned short* xh   = (unsigned short*)ws; ws += (size_t)BN_NODES * DIM * 2; // 4 MB
    int*   counts     = (int*)ws;          ws += (size_t)BN_NODES * 4;
    int*   bin_cursor = (int*)ws;          ws += (size_t)NBINS * 4;
    uint2* staging    = (uint2*)ws;        ws += (size_t)NBINS * CAPB * 8;        // 6 MB

    int histBlocks = (nE + 255) / 256;
    int binABlocks = (nE + EPB - 1) / EPB;
    hipMemsetAsync(counts, 0, (size_t)BN_NODES * 4, stream);
    prep_kernel<<<1376 + histBlocks + 1, 256, 0, stream>>>(W1, b1, W2, b2, W3, W4, h, ei,
                                                           Tb2, w3t, w4t, xh, counts,
                                                           bin_cursor, nE);
    binA_kernel<<<binABlocks, 512, 0, stream>>>(ei, x, bin_cursor, staging, nE);
    mega_kernel<<<NBINS, 512, 0, stream>>>(staging, counts, Tb2, xh,
                                           w3t, b3, gamma, beta, w4t, b4, out);
}

// Round 11
// 177.540 us; speedup vs baseline: 1.0460x; 1.0460x over previous
//
#include <hip/hip_runtime.h>
#include <hip/hip_fp16.h>
#include <math.h>

// Problem constants (fixed by the reference)
#define BN_NODES 16384     // B*N
#define DIM 128            // D
#define HID 256            // H
#define TK 4096            // distance-table knots (nearest-neighbor)
#define TRANGE 32.0f
#define TSTEP (TRANGE / (float)TK)   // 1/128
#define TINV  ((float)TK / TRANGE)   // 128
#define LN_EPS 1e-5f
#define EPB 4096           // edges per block in binA
#define NBINS 1024         // 16-node bins
#define CAPB 768           // staging capacity per bin (mean 512, +11 sigma)

typedef _Float16 f16x8 __attribute__((ext_vector_type(8)));
typedef __attribute__((ext_vector_type(4))) float f32x4;
typedef __attribute__((ext_vector_type(2))) float floatx2;
typedef __attribute__((ext_vector_type(8))) unsigned short ushort8v;

__device__ __forceinline__ unsigned short f2h(float f) {
    _Float16 h = (_Float16)f;          // v_cvt_f16_f32, RNE
    return *(unsigned short*)&h;
}
__device__ __forceinline__ __half2 u2h2(unsigned int u) {
    union { unsigned int u; __half2 h; } c; c.u = u; return c.h;
}

// per-edge message accumulate (fp32 chains):
//   rec = (r4<<26)|(c<<14bits...): c=(rec>>12)&0x3FFF, k=rec&0xFFF
//   1 ushort gather (2 fp8 dims of h) + 1 dword gather (2 fp16 table dims)
__device__ __forceinline__ void edge_acc(unsigned int rec, int dd,
        const unsigned char* __restrict__ xq,
        const unsigned short* __restrict__ Tb, float& a0, float& a1) {
    int c = (int)((rec >> 12) & 0x3FFFu);
    int k = (int)(rec & 0xFFFu);
    unsigned short hq = *(const unsigned short*)&xq[c * DIM + dd];
    unsigned int tv = *(const unsigned int*)&Tb[k * DIM + dd];
    floatx2 hf = __builtin_amdgcn_cvt_pk_f32_fp8((int)hq, false);
    __half2 th = u2h2(tv);
    a0 = fmaf(hf[0], __low2float(th), a0);
    a1 = fmaf(hf[1], __high2float(th), a1);
}

__device__ __forceinline__ void node_tail(const unsigned int* lrec, int from, int to,
        int dd, const unsigned char* __restrict__ xq,
        const unsigned short* __restrict__ Tb, float& a0, float& a1) {
    int i = from;
    for (; i + 4 <= to; i += 4) {
        unsigned int e0 = lrec[i], e1 = lrec[i + 1], e2 = lrec[i + 2], e3 = lrec[i + 3];
        edge_acc(e0, dd, xq, Tb, a0, a1);
        edge_acc(e1, dd, xq, Tb, a0, a1);
        edge_acc(e2, dd, xq, Tb, a0, a1);
        edge_acc(e3, dd, xq, Tb, a0, a1);
    }
    for (; i < to; ++i) edge_acc(lrec[i], dd, xq, Tb, a0, a1);
}

// ---------------------------------------------------------------------------
// K1 "prep": blocks 0..511 build nearest-neighbor fp16 table Tb[4096][128]
// (evaluated at cell centers (k+0.5)*TSTEP); 512..575 transpose W3 -> w3t;
// 576..607 W4 -> w4t; 608..1631 h -> xh fp16 AND xq fp8-e4m3;
// 1632..1632+hb-1 histogram; last block: bin cursor init.
__global__ __launch_bounds__(256) void prep_kernel(
        const float* __restrict__ W1, const float* __restrict__ b1,
        const float* __restrict__ W2, const float* __restrict__ b2,
        const float* __restrict__ W3, const float* __restrict__ W4,
        const float* __restrict__ h, const int* __restrict__ ei,
        unsigned short* __restrict__ Tb, unsigned short* __restrict__ w3t,
        unsigned short* __restrict__ w4t, unsigned short* __restrict__ xh,
        unsigned char* __restrict__ xq, int* __restrict__ counts,
        int* __restrict__ bin_cursor, int nE) {
    __shared__ float smem[8 * 256 + 8 * 128];   // 12 KB, role-dependent
    int bid = blockIdx.x, t = threadIdx.x;
    int hb = (nE + 255) >> 8;
    if (bid < 512) {
        float* a    = smem;            // [8][256]
        float* part = smem + 8 * 256;  // [8][128]
        int k0 = bid * 8;
        float w1 = W1[t], bb = b1[t];
#pragma unroll
        for (int k = 0; k < 8; ++k) {
            float dist = ((float)(k0 + k) + 0.5f) * TSTEP;   // cell center
            float z = dist * w1 + bb;
            a[k * 256 + t] = z / (1.0f + expf(-z));
        }
        __syncthreads();
        int hg = t >> 7, d = t & 127;
        float acc[8] = {0.f,0.f,0.f,0.f,0.f,0.f,0.f,0.f};
        for (int hh = 0; hh < 128; ++hh) {
            int hidx = hg * 128 + hh;
            float w = W2[hidx * DIM + d];
#pragma unroll
            for (int k = 0; k < 8; ++k) acc[k] += a[k * 256 + hidx] * w;
        }
        if (hg == 1) {
#pragma unroll
            for (int k = 0; k < 8; ++k) part[k * 128 + d] = acc[k];
        }
        __syncthreads();
        if (hg == 0) {
            float bd = b2[d];
#pragma unroll
            for (int k = 0; k < 8; ++k)
                Tb[(k0 + k) * DIM + d] = f2h(acc[k] + part[k * 128 + d] + bd);
        }
    } else if (bid < 576) {
        float* s = smem;   // [32][33]
        int tid = bid - 512, tr = tid >> 3, tc = tid & 7;
        int lr = t >> 5, lc = t & 31;
#pragma unroll
        for (int rep = 0; rep < 4; ++rep) {
            int k = tr * 32 + rep * 8 + lr, n = tc * 32 + lc;
            s[lc * 33 + rep * 8 + lr] = W3[k * 256 + n];
        }
        __syncthreads();
#pragma unroll
        for (int rep = 0; rep < 4; ++rep) {
            int n = tc * 32 + rep * 8 + lr, k = tr * 32 + lc;
            w3t[n * 256 + k] = f2h(s[(rep * 8 + lr) * 33 + lc]);
        }
    } else if (bid < 608) {
        float* s = smem;
        int tid = bid - 576, tr = tid >> 2, tc = tid & 3;
        int lr = t >> 5, lc = t & 31;
#pragma unroll
        for (int rep = 0; rep < 4; ++rep) {
            int k = tr * 32 + rep * 8 + lr, n = tc * 32 + lc;
            s[lc * 33 + rep * 8 + lr] = W4[k * 128 + n];
        }
        __syncthreads();
#pragma unroll
        for (int rep = 0; rep < 4; ++rep) {
            int n = tc * 32 + rep * 8 + lr, k = tr * 32 + lc;
            w4t[n * 256 + k] = f2h(s[(rep * 8 + lr) * 33 + lc]);
        }
    } else if (bid < 1632) {
        int i0 = (bid - 608) * 2048 + t * 8;
        float4 v0 = *(const float4*)&h[i0];
        float4 v1 = *(const float4*)&h[i0 + 4];
        ushort8v o;
        o[0] = f2h(v0.x); o[1] = f2h(v0.y); o[2] = f2h(v0.z); o[3] = f2h(v0.w);
        o[4] = f2h(v1.x); o[5] = f2h(v1.y); o[6] = f2h(v1.z); o[7] = f2h(v1.w);
        *(ushort8v*)&xh[i0] = o;
        unsigned int q0 = 0, q1 = 0;
        q0 = __builtin_amdgcn_cvt_pk_fp8_f32(v0.x, v0.y, q0, false);
        q0 = __builtin_amdgcn_cvt_pk_fp8_f32(v0.z, v0.w, q0, true);
        q1 = __builtin_amdgcn_cvt_pk_fp8_f32(v1.x, v1.y, q1, false);
        q1 = __builtin_amdgcn_cvt_pk_fp8_f32(v1.z, v1.w, q1, true);
        uint2 qq; qq.x = q0; qq.y = q1;
        *(uint2*)&xq[i0] = qq;
    } else if (bid < 1632 + hb) {
        int e = (bid - 1632) * 256 + t;
        if (e < nE) atomicAdd(&counts[ei[e]], 1);
    } else {
        for (int i = t; i < NBINS; i += 256) bin_cursor[i] = i * CAPB;
    }
}

// ---------------------------------------------------------------------------
// K2: bin scatter + edge precompute. 512 threads; LDS counting-sort 4096-edge
// chunks into 1024 bins (bin = row>>4); at write-out compute dist -> knot k,
// emit ONE dword (r4<<26 | c<<12 | k) into the bin's fixed staging region.
__global__ __launch_bounds__(512) void binA_kernel(
        const int* __restrict__ ei, const float* __restrict__ x,
        int* __restrict__ bin_cursor, unsigned int* __restrict__ staging, int nE) {
    __shared__ int cnt[NBINS];
    __shared__ int pre[NBINS];
    __shared__ int gbase[NBINS];
    __shared__ int sc[512];
    __shared__ unsigned int rec[EPB];   // 16 KB
    int t = threadIdx.x;
    int e0 = blockIdx.x * EPB;
    int m = min(EPB, nE - e0);
    cnt[t] = 0; cnt[t + 512] = 0;
    __syncthreads();
    unsigned int code[8];
    int rk[8], bn[8];
#pragma unroll
    for (int j = 0; j < 8; ++j) {
        int idx = j * 512 + t;
        rk[j] = -1; bn[j] = 0; code[j] = 0;
        if (idx < m) {
            int e = e0 + idx;
            int r = ei[e], c = ei[nE + e];
            code[j] = ((unsigned int)r << 14) | (unsigned int)c;   // 28 bits
            bn[j] = r >> 4;
            rk[j] = atomicAdd(&cnt[bn[j]], 1);
        }
    }
    __syncthreads();
    int c0 = cnt[2 * t], c1 = cnt[2 * t + 1];
    int s2 = c0 + c1;
    sc[t] = s2;
    __syncthreads();
    for (int off = 1; off < 512; off <<= 1) {
        int v = (t >= off) ? sc[t - off] : 0;
        __syncthreads();
        sc[t] += v;
        __syncthreads();
    }
    int excl = sc[t] - s2;
    pre[2 * t]     = excl;
    pre[2 * t + 1] = excl + c0;
    gbase[2 * t]     = atomicAdd(&bin_cursor[2 * t], c0);
    gbase[2 * t + 1] = atomicAdd(&bin_cursor[2 * t + 1], c1);
    __syncthreads();
#pragma unroll
    for (int j = 0; j < 8; ++j)
        if (rk[j] >= 0) rec[pre[bn[j]] + rk[j]] = code[j];
    __syncthreads();
    for (int i = t; i < m; i += 512) {
        unsigned int cd = rec[i];
        int b = (int)(cd >> 18);            // row >> 4
        int r = (int)(cd >> 14);
        int c = (int)(cd & 0x3FFFu);
        float dx = x[r * 3 + 0] - x[c * 3 + 0];
        float dy = x[r * 3 + 1] - x[c * 3 + 1];
        float dz = x[r * 3 + 2] - x[c * 3 + 2];
        float u = sqrtf(dx * dx + dy * dy + dz * dz) * TINV;
        int k = min((int)u, TK - 1);
        unsigned int o = ((unsigned int)(r & 15) << 26)
                       | ((unsigned int)c << 12) | (unsigned int)k;
        int idx = gbase[b] + (i - pre[b]);
        if (idx < (b + 1) * CAPB) staging[idx] = o;   // 11-sigma guard
    }
}

// ---------------------------------------------------------------------------
// K3 "mega": 1024 blocks x 512 threads, 16 nodes/block, 4 blocks/CU.
// Per-edge gather working set is now L2-resident (xq fp8 2MB + Tb 1MB < 4MB
// per-XCD L2 — R9/R10 thrashed 5MB and was L3-latency-bound at ~10 TB/s).
// Phase 2 accumulates in fp32 (fp8 h x fp16 nearest-table filter).
__global__ __launch_bounds__(512, 8) void mega_kernel(
        const unsigned int* __restrict__ staging, const int* __restrict__ counts,
        const unsigned short* __restrict__ Tb, const unsigned char* __restrict__ xq,
        const unsigned short* __restrict__ xh, const unsigned short* __restrict__ w3t,
        const float* __restrict__ b3, const float* __restrict__ gamma,
        const float* __restrict__ beta, const unsigned short* __restrict__ w4t,
        const float* __restrict__ b4, float* __restrict__ out) {
    __shared__ unsigned int lrec[CAPB];                     // 3 KB
    __shared__ int pref[17];
    __shared__ int cur[16];
    __shared__ __align__(16) unsigned short aggh[16][136];  // 4.25 KB
    __shared__ __align__(16) unsigned short a_lds[16][264]; // 8.25 KB
    __shared__ float part_s[8][16], part_q[8][16];          // 1 KB
    __shared__ float tot_mu[16], tot_rs[16];

    int t = threadIdx.x;
    int bin = blockIdx.x;
    int n0 = bin * 16;

    // ---- phase 0: per-node exclusive prefix within bin (16 lanes)
    if (t < 16) {
        int c = counts[n0 + t];
        int s = c;
#pragma unroll
        for (int off = 1; off < 16; off <<= 1) {
            int v = __shfl_up(s, off, 16);
            if (t >= off) s += v;
        }
        pref[t + 1] = s;
        cur[t] = s - c;
        if (t == 0) pref[0] = 0;
    }
    __syncthreads();
    int total = min(pref[16], CAPB);
    long base = (long)bin * CAPB;

    // ---- phase 1: staging -> LDS records in CSR order
    for (int i = t; i < total; i += 512) {
        unsigned int sr = staging[base + i];
        int r4 = (int)(sr >> 26);
        int pos = atomicAdd(&cur[r4], 1);
        lrec[pos] = sr;
    }
    __syncthreads();

    int wid = t >> 6, lane = t & 63, dd = lane * 2;

    // ---- phase 2: wave wid owns nodes wid*2, wid*2+1 (interleaved bulk)
    {
        int j0 = wid * 2, j1 = j0 + 1;
        int off0 = pref[j0], len0 = pref[j0 + 1] - off0;
        int off1 = pref[j1], len1 = pref[j1 + 1] - off1;
        float a0x = 0.f, a0y = 0.f, a1x = 0.f, a1y = 0.f;
        int minl = min(len0, len1);
        int i = 0;
        for (; i + 4 <= minl; i += 4) {
            unsigned int ea0 = lrec[off0 + i],     eb0 = lrec[off1 + i];
            unsigned int ea1 = lrec[off0 + i + 1], eb1 = lrec[off1 + i + 1];
            unsigned int ea2 = lrec[off0 + i + 2], eb2 = lrec[off1 + i + 2];
            unsigned int ea3 = lrec[off0 + i + 3], eb3 = lrec[off1 + i + 3];
            edge_acc(ea0, dd, xq, Tb, a0x, a0y); edge_acc(eb0, dd, xq, Tb, a1x, a1y);
            edge_acc(ea1, dd, xq, Tb, a0x, a0y); edge_acc(eb1, dd, xq, Tb, a1x, a1y);
            edge_acc(ea2, dd, xq, Tb, a0x, a0y); edge_acc(eb2, dd, xq, Tb, a1x, a1y);
            edge_acc(ea3, dd, xq, Tb, a0x, a0y); edge_acc(eb3, dd, xq, Tb, a1x, a1y);
        }
        node_tail(lrec, off0 + i, off0 + len0, dd, xq, Tb, a0x, a0y);
        node_tail(lrec, off1 + i, off1 + len1, dd, xq, Tb, a1x, a1y);
        float inv0 = 1.0f / (float)max(len0, 1);
        float inv1 = 1.0f / (float)max(len1, 1);
        unsigned int p0 = (unsigned int)f2h(a0x * inv0) | ((unsigned int)f2h(a0y * inv0) << 16);
        unsigned int p1 = (unsigned int)f2h(a1x * inv1) | ((unsigned int)f2h(a1y * inv1) << 16);
        *(unsigned int*)&aggh[j0][dd] = p0;
        *(unsigned int*)&aggh[j1][dd] = p1;
    }
    __syncthreads();

    // ---- phase 3: GEMM1: U[16,256] = [xh | aggh] @ W3; wave owns 32 cols
    int wv = wid, q = lane >> 4, l15 = lane & 15;
    f32x4 acc[2];
    acc[0] = (f32x4){0.f, 0.f, 0.f, 0.f};
    acc[1] = (f32x4){0.f, 0.f, 0.f, 0.f};
    for (int kc = 0; kc < 8; ++kc) {
        f16x8 a;
        if (kc < 4) a = *(const f16x8*)&xh[(n0 + l15) * DIM + kc * 32 + q * 8];
        else        a = *(const f16x8*)&aggh[l15][(kc - 4) * 32 + q * 8];
#pragma unroll
        for (int nt = 0; nt < 2; ++nt) {
            f16x8 b = *(const f16x8*)&w3t[(wv * 32 + nt * 16 + l15) * 256 + kc * 32 + q * 8];
            acc[nt] = __builtin_amdgcn_mfma_f32_16x16x32_f16(a, b, acc[nt], 0, 0, 0);
        }
    }

    // bias + LN stats (intra-16-lane shfl, then cross-wave LDS sum)
    float b3v[2], gv[2], bvv[2];
#pragma unroll
    for (int nt = 0; nt < 2; ++nt) {
        int col = wv * 32 + nt * 16 + l15;
        b3v[nt] = b3[col]; gv[nt] = gamma[col]; bvv[nt] = beta[col];
    }
    {
        float s_[4], q_[4];
#pragma unroll
        for (int reg = 0; reg < 4; ++reg) {
            float su = 0.f, sq = 0.f;
#pragma unroll
            for (int nt = 0; nt < 2; ++nt) {
                float v = acc[nt][reg] + b3v[nt];
                acc[nt][reg] = v;
                su += v; sq += v * v;
            }
            s_[reg] = su; q_[reg] = sq;
        }
#pragma unroll
        for (int off = 1; off < 16; off <<= 1) {
#pragma unroll
            for (int reg = 0; reg < 4; ++reg) {
                s_[reg] += __shfl_xor(s_[reg], off, 64);
                q_[reg] += __shfl_xor(q_[reg], off, 64);
            }
        }
        if (l15 == 0) {
#pragma unroll
            for (int reg = 0; reg < 4; ++reg) {
                int r = q * 4 + reg;
                part_s[wv][r] = s_[reg];
                part_q[wv][r] = q_[reg];
            }
        }
    }
    __syncthreads();
    if (t < 16) {
        float st = 0.f, qt = 0.f;
#pragma unroll
        for (int w = 0; w < 8; ++w) { st += part_s[w][t]; qt += part_q[w][t]; }
        float mu = st * (1.0f / 256.0f);
        float var = qt * (1.0f / 256.0f) - mu * mu;
        tot_mu[t] = mu;
        tot_rs[t] = rsqrtf(var + LN_EPS);
    }
    __syncthreads();

    // LN + SiLU -> fp16 act in LDS (A-operand layout [m][k])
#pragma unroll
    for (int reg = 0; reg < 4; ++reg) {
        int r = q * 4 + reg;
        float mu = tot_mu[r], rs = tot_rs[r];
#pragma unroll
        for (int nt = 0; nt < 2; ++nt) {
            float un = (acc[nt][reg] - mu) * rs * gv[nt] + bvv[nt];
            float act = un / (1.0f + expf(-un));
            a_lds[r][wv * 32 + nt * 16 + l15] = f2h(act);
        }
    }
    __syncthreads();

    // GEMM2: out[16,128] = act @ W4; wave wv owns cols wv*16..+15
    f32x4 acc2 = (f32x4){0.f, 0.f, 0.f, 0.f};
    int col2 = wv * 16 + l15;
    for (int kc = 0; kc < 8; ++kc) {
        f16x8 a = *(const f16x8*)&a_lds[l15][kc * 32 + q * 8];
        f16x8 b = *(const f16x8*)&w4t[col2 * 256 + kc * 32 + q * 8];
        acc2 = __builtin_amdgcn_mfma_f32_16x16x32_f16(a, b, acc2, 0, 0, 0);
    }
    float b4v = b4[col2];
#pragma unroll
    for (int reg = 0; reg < 4; ++reg) {
        int node = n0 + q * 4 + reg;
        out[node * DIM + col2] = acc2[reg] + b4v;
    }
}

// ---------------------------------------------------------------------------
extern "C" void kernel_launch(void* const* d_in, const int* in_sizes, int n_in,
                              void* d_out, int out_size, void* d_ws, size_t ws_size,
                              hipStream_t stream) {
    const float* x     = (const float*)d_in[0];
    const float* h     = (const float*)d_in[1];
    const int*   ei    = (const int*)d_in[2];
    const float* W1    = (const float*)d_in[4];
    const float* b1    = (const float*)d_in[5];
    const float* W2    = (const float*)d_in[6];
    const float* b2    = (const float*)d_in[7];
    const float* W3    = (const float*)d_in[8];
    const float* b3    = (const float*)d_in[9];
    const float* gamma = (const float*)d_in[10];
    const float* beta  = (const float*)d_in[11];
    const float* W4    = (const float*)d_in[12];
    const float* b4    = (const float*)d_in[13];
    float* out = (float*)d_out;
    int nE = in_sizes[2] / 2;

    char* ws = (char*)d_ws;
    unsigned short* Tb   = (unsigned short*)ws; ws += (size_t)TK * DIM * 2;       // 1 MB
    unsigned short* w3t  = (unsigned short*)ws; ws += (size_t)HID * HID * 2;      // 128 KB
    unsigned short* w4t  = (unsigned short*)ws; ws += (size_t)DIM * HID * 2;      // 64 KB
    unsigned short* xh   = (unsigned short*)ws; ws += (size_t)BN_NODES * DIM * 2; // 4 MB
    unsigned char*  xq   = (unsigned char*)ws;  ws += (size_t)BN_NODES * DIM;     // 2 MB
    int*   counts     = (int*)ws;          ws += (size_t)BN_NODES * 4;
    int*   bin_cursor = (int*)ws;          ws += (size_t)NBINS * 4;
    unsigned int* staging = (unsigned int*)ws; ws += (size_t)NBINS * CAPB * 4;    // 3 MB

    int histBlocks = (nE + 255) / 256;
    int binABlocks = (nE + EPB - 1) / EPB;
    hipMemsetAsync(counts, 0, (size_t)BN_NODES * 4, stream);
    prep_kernel<<<1632 + histBlocks + 1, 256, 0, stream>>>(W1, b1, W2, b2, W3, W4, h, ei,
                                                           Tb, w3t, w4t, xh, xq, counts,
                                                           bin_cursor, nE);
    binA_kernel<<<binABlocks, 512, 0, stream>>>(ei, x, bin_cursor, staging, nE);
    mega_kernel<<<NBINS, 512, 0, stream>>>(staging, counts, Tb, xq, xh,
                                           w3t, b3, gamma, beta, w4t, b4, out);
}

// Round 12
// 161.537 us; speedup vs baseline: 1.1496x; 1.0991x over previous
//
#include <hip/hip_runtime.h>
#include <hip/hip_fp16.h>
#include <math.h>

// Problem constants (fixed by the reference)
#define BN_NODES 16384     // B*N
#define DIM 128            // D
#define HID 256            // H
#define TK 4096            // distance-table knots (nearest-neighbor)
#define TRANGE 32.0f
#define TSTEP (TRANGE / (float)TK)   // 1/128
#define TINV  ((float)TK / TRANGE)   // 128
#define LN_EPS 1e-5f
#define EPB 4096           // edges per binning block
#define NBINS 1024         // 16-node bins
#define CAPB 768           // staging capacity per bin (mean 512, +11 sigma)

typedef _Float16 f16x8 __attribute__((ext_vector_type(8)));
typedef __attribute__((ext_vector_type(4))) float f32x4;
typedef __attribute__((ext_vector_type(2))) float floatx2;
typedef __attribute__((ext_vector_type(8))) unsigned short ushort8v;

__device__ __forceinline__ unsigned short f2h(float f) {
    _Float16 h = (_Float16)f;          // v_cvt_f16_f32, RNE
    return *(unsigned short*)&h;
}
__device__ __forceinline__ __half2 u2h2(unsigned int u) {
    union { unsigned int u; __half2 h; } c; c.u = u; return c.h;
}

// per-edge message accumulate (fp32 chains):
//   rec = r4<<26 | c<<12 | k ;  1 ushort gather (2 fp8 dims of h) +
//   1 dword gather (2 fp16 nearest-table dims)
__device__ __forceinline__ void edge_acc(unsigned int rec, int dd,
        const unsigned char* __restrict__ xq,
        const unsigned short* __restrict__ Tb, float& a0, float& a1) {
    int c = (int)((rec >> 12) & 0x3FFFu);
    int k = (int)(rec & 0xFFFu);
    unsigned short hq = *(const unsigned short*)&xq[c * DIM + dd];
    unsigned int tv = *(const unsigned int*)&Tb[k * DIM + dd];
    floatx2 hf = __builtin_amdgcn_cvt_pk_f32_fp8((int)hq, false);
    __half2 th = u2h2(tv);
    a0 = fmaf(hf[0], __low2float(th), a0);
    a1 = fmaf(hf[1], __high2float(th), a1);
}

__device__ __forceinline__ void node_tail(const unsigned int* lrec, int from, int to,
        int dd, const unsigned char* __restrict__ xq,
        const unsigned short* __restrict__ Tb, float& a0, float& a1) {
    int i = from;
    for (; i + 4 <= to; i += 4) {
        unsigned int e0 = lrec[i], e1 = lrec[i + 1], e2 = lrec[i + 2], e3 = lrec[i + 3];
        edge_acc(e0, dd, xq, Tb, a0, a1);
        edge_acc(e1, dd, xq, Tb, a0, a1);
        edge_acc(e2, dd, xq, Tb, a0, a1);
        edge_acc(e3, dd, xq, Tb, a0, a1);
    }
    for (; i < to; ++i) edge_acc(lrec[i], dd, xq, Tb, a0, a1);
}

// ---------------------------------------------------------------------------
// K1 "prep" (fully fused; binning merged in — it depends on no other role):
//   blocks 0..511     : nearest-neighbor fp16 table Tb[4096][128] (cell centers)
//   512..575          : W3 -> w3t[n][k] fp16 transpose
//   576..607          : W4 -> w4t[n][k] fp16 transpose
//   608..1631         : h -> xh fp16 AND xq fp8-e4m3
//   1632..            : edge binning: LDS counting-sort EPB-edge chunks into
//                       1024 bins (bin=row>>4), compute dist -> knot k, write
//                       rec = r4<<26|c<<12|k to staging[bin*CAPB + off].
//                       bin_cursor (zeroed by memset) reserves per-bin space
//                       AND ends up holding each bin's edge count for mega.
__global__ __launch_bounds__(256) void prep_kernel(
        const float* __restrict__ W1, const float* __restrict__ b1,
        const float* __restrict__ W2, const float* __restrict__ b2,
        const float* __restrict__ W3, const float* __restrict__ W4,
        const float* __restrict__ h, const int* __restrict__ ei,
        const float* __restrict__ x,
        unsigned short* __restrict__ Tb, unsigned short* __restrict__ w3t,
        unsigned short* __restrict__ w4t, unsigned short* __restrict__ xh,
        unsigned char* __restrict__ xq, int* __restrict__ bin_cursor,
        unsigned int* __restrict__ staging, int nE) {
    __shared__ float smem[8 * 256 + 8 * 128];   // 12 KB (table role)
    int bid = blockIdx.x, t = threadIdx.x;
    if (bid < 512) {
        float* a    = smem;            // [8][256]
        float* part = smem + 8 * 256;  // [8][128]
        int k0 = bid * 8;
        float w1 = W1[t], bb = b1[t];
#pragma unroll
        for (int k = 0; k < 8; ++k) {
            float dist = ((float)(k0 + k) + 0.5f) * TSTEP;   // cell center
            float z = dist * w1 + bb;
            a[k * 256 + t] = z / (1.0f + expf(-z));
        }
        __syncthreads();
        int hg = t >> 7, d = t & 127;
        float acc[8] = {0.f,0.f,0.f,0.f,0.f,0.f,0.f,0.f};
        for (int hh = 0; hh < 128; ++hh) {
            int hidx = hg * 128 + hh;
            float w = W2[hidx * DIM + d];
#pragma unroll
            for (int k = 0; k < 8; ++k) acc[k] += a[k * 256 + hidx] * w;
        }
        if (hg == 1) {
#pragma unroll
            for (int k = 0; k < 8; ++k) part[k * 128 + d] = acc[k];
        }
        __syncthreads();
        if (hg == 0) {
            float bd = b2[d];
#pragma unroll
            for (int k = 0; k < 8; ++k)
                Tb[(k0 + k) * DIM + d] = f2h(acc[k] + part[k * 128 + d] + bd);
        }
    } else if (bid < 576) {
        float* s = smem;   // [32][33]
        int tid = bid - 512, tr = tid >> 3, tc = tid & 7;
        int lr = t >> 5, lc = t & 31;
#pragma unroll
        for (int rep = 0; rep < 4; ++rep) {
            int k = tr * 32 + rep * 8 + lr, n = tc * 32 + lc;
            s[lc * 33 + rep * 8 + lr] = W3[k * 256 + n];
        }
        __syncthreads();
#pragma unroll
        for (int rep = 0; rep < 4; ++rep) {
            int n = tc * 32 + rep * 8 + lr, k = tr * 32 + lc;
            w3t[n * 256 + k] = f2h(s[(rep * 8 + lr) * 33 + lc]);
        }
    } else if (bid < 608) {
        float* s = smem;
        int tid = bid - 576, tr = tid >> 2, tc = tid & 3;
        int lr = t >> 5, lc = t & 31;
#pragma unroll
        for (int rep = 0; rep < 4; ++rep) {
            int k = tr * 32 + rep * 8 + lr, n = tc * 32 + lc;
            s[lc * 33 + rep * 8 + lr] = W4[k * 128 + n];
        }
        __syncthreads();
#pragma unroll
        for (int rep = 0; rep < 4; ++rep) {
            int n = tc * 32 + rep * 8 + lr, k = tr * 32 + lc;
            w4t[n * 256 + k] = f2h(s[(rep * 8 + lr) * 33 + lc]);
        }
    } else if (bid < 1632) {
        int i0 = (bid - 608) * 2048 + t * 8;
        float4 v0 = *(const float4*)&h[i0];
        float4 v1 = *(const float4*)&h[i0 + 4];
        ushort8v o;
        o[0] = f2h(v0.x); o[1] = f2h(v0.y); o[2] = f2h(v0.z); o[3] = f2h(v0.w);
        o[4] = f2h(v1.x); o[5] = f2h(v1.y); o[6] = f2h(v1.z); o[7] = f2h(v1.w);
        *(ushort8v*)&xh[i0] = o;
        unsigned int q0 = 0, q1 = 0;
        q0 = __builtin_amdgcn_cvt_pk_fp8_f32(v0.x, v0.y, q0, false);
        q0 = __builtin_amdgcn_cvt_pk_fp8_f32(v0.z, v0.w, q0, true);
        q1 = __builtin_amdgcn_cvt_pk_fp8_f32(v1.x, v1.y, q1, false);
        q1 = __builtin_amdgcn_cvt_pk_fp8_f32(v1.z, v1.w, q1, true);
        uint2 qq; qq.x = q0; qq.y = q1;
        *(uint2*)&xq[i0] = qq;
    } else {
        // ---- edge binning role (ex-binA), 256 threads, EPB=4096 edges
        __shared__ int cnt[NBINS];              // reuse own LDS (4 KB)
        __shared__ int pre[NBINS];
        __shared__ int gba[NBINS];
        __shared__ int sc[256];
        __shared__ unsigned int rec[EPB];       // 16 KB
        int e0 = (bid - 1632) * EPB;
        int m = min(EPB, nE - e0);
        if (m < 0) m = 0;
#pragma unroll
        for (int j = 0; j < 4; ++j) cnt[j * 256 + t] = 0;
        __syncthreads();
        unsigned int code[16];
        int rk[16], bn[16];
#pragma unroll
        for (int j = 0; j < 16; ++j) {
            int idx = j * 256 + t;
            rk[j] = -1; bn[j] = 0; code[j] = 0;
            if (idx < m) {
                int e = e0 + idx;
                int r = ei[e], c = ei[nE + e];
                code[j] = ((unsigned int)r << 14) | (unsigned int)c;   // 28 bits
                bn[j] = r >> 4;
                rk[j] = atomicAdd(&cnt[bn[j]], 1);
            }
        }
        __syncthreads();
        int c4[4], s4 = 0;
#pragma unroll
        for (int j = 0; j < 4; ++j) { c4[j] = cnt[t * 4 + j]; s4 += c4[j]; }
        sc[t] = s4;
        __syncthreads();
        for (int off = 1; off < 256; off <<= 1) {
            int v = (t >= off) ? sc[t - off] : 0;
            __syncthreads();
            sc[t] += v;
            __syncthreads();
        }
        int run = sc[t] - s4;
#pragma unroll
        for (int j = 0; j < 4; ++j) {
            int b = t * 4 + j;
            pre[b] = run; run += c4[j];
            gba[b] = atomicAdd(&bin_cursor[b], c4[j]);
        }
        __syncthreads();
#pragma unroll
        for (int j = 0; j < 16; ++j)
            if (rk[j] >= 0) rec[pre[bn[j]] + rk[j]] = code[j];
        __syncthreads();
        for (int i = t; i < m; i += 256) {
            unsigned int cd = rec[i];
            int b = (int)(cd >> 18);            // row >> 4
            int r = (int)(cd >> 14);
            int c = (int)(cd & 0x3FFFu);
            float dx = x[r * 3 + 0] - x[c * 3 + 0];
            float dy = x[r * 3 + 1] - x[c * 3 + 1];
            float dz = x[r * 3 + 2] - x[c * 3 + 2];
            float u = sqrtf(dx * dx + dy * dy + dz * dz) * TINV;
            int k = min((int)u, TK - 1);
            unsigned int o = ((unsigned int)(r & 15) << 26)
                           | ((unsigned int)c << 12) | (unsigned int)k;
            int off = gba[b] + (i - pre[b]);
            if (off < CAPB) staging[b * CAPB + off] = o;   // 11-sigma guard
        }
    }
}

// ---------------------------------------------------------------------------
// K2 "mega": 1024 blocks x 512 threads, 16 nodes/block, 4 blocks/CU.
// Per-edge gather working set is L2-resident (xq fp8 2MB + Tb 1MB < 4MB/XCD).
// Phase 0/1: derive per-node counts from the staging slice itself (two LDS
// passes, records register-cached) — the global histogram kernel is gone.
// Phase 2: wave owns 2 nodes, 8-edge x 2-node interleaved bulk (32 loads in
// flight). Phase 3: MFMA GEMM1 -> LN -> SiLU -> GEMM2 -> out.
__global__ __launch_bounds__(512, 8) void mega_kernel(
        const unsigned int* __restrict__ staging, const int* __restrict__ bin_cursor,
        const unsigned short* __restrict__ Tb, const unsigned char* __restrict__ xq,
        const unsigned short* __restrict__ xh, const unsigned short* __restrict__ w3t,
        const float* __restrict__ b3, const float* __restrict__ gamma,
        const float* __restrict__ beta, const unsigned short* __restrict__ w4t,
        const float* __restrict__ b4, float* __restrict__ out) {
    __shared__ unsigned int lrec[CAPB];                     // 3 KB
    __shared__ int cnt16[16];
    __shared__ int pref[17];
    __shared__ int cur[16];
    __shared__ __align__(16) unsigned short aggh[16][136];  // 4.25 KB
    __shared__ __align__(16) unsigned short a_lds[16][264]; // 8.25 KB
    __shared__ float part_s[8][16], part_q[8][16];          // 1 KB
    __shared__ float tot_mu[16], tot_rs[16];

    int t = threadIdx.x;
    int bin = blockIdx.x;
    int n0 = bin * 16;
    if (t < 16) cnt16[t] = 0;
    __syncthreads();
    int total = min(bin_cursor[bin], CAPB);
    long base = (long)bin * CAPB;

    // ---- phase 0: count pass (records cached in registers; total<=768<1024)
    unsigned int sr0 = 0, sr1 = 0;
    int have0 = (t < total), have1 = (t + 512 < total);
    if (have0) { sr0 = staging[base + t];       atomicAdd(&cnt16[sr0 >> 26], 1); }
    if (have1) { sr1 = staging[base + t + 512]; atomicAdd(&cnt16[sr1 >> 26], 1); }
    __syncthreads();
    if (t < 16) {
        int c = cnt16[t];
        int s = c;
#pragma unroll
        for (int off = 1; off < 16; off <<= 1) {
            int v = __shfl_up(s, off, 16);
            if (t >= off) s += v;
        }
        pref[t + 1] = s;
        cur[t] = s - c;
        if (t == 0) pref[0] = 0;
    }
    __syncthreads();

    // ---- phase 1: scatter into CSR order
    if (have0) { int pos = atomicAdd(&cur[sr0 >> 26], 1); lrec[pos] = sr0; }
    if (have1) { int pos = atomicAdd(&cur[sr1 >> 26], 1); lrec[pos] = sr1; }
    __syncthreads();

    int wid = t >> 6, lane = t & 63, dd = lane * 2;

    // ---- phase 2: wave wid owns nodes wid*2, wid*2+1 (8x2 interleaved bulk)
    {
        int j0 = wid * 2, j1 = j0 + 1;
        int off0 = pref[j0], len0 = pref[j0 + 1] - off0;
        int off1 = pref[j1], len1 = pref[j1 + 1] - off1;
        float a0x = 0.f, a0y = 0.f, a1x = 0.f, a1y = 0.f;
        int minl = min(len0, len1);
        int i = 0;
        for (; i + 8 <= minl; i += 8) {
#pragma unroll
            for (int u = 0; u < 8; ++u) {
                edge_acc(lrec[off0 + i + u], dd, xq, Tb, a0x, a0y);
                edge_acc(lrec[off1 + i + u], dd, xq, Tb, a1x, a1y);
            }
        }
        node_tail(lrec, off0 + i, off0 + len0, dd, xq, Tb, a0x, a0y);
        node_tail(lrec, off1 + i, off1 + len1, dd, xq, Tb, a1x, a1y);
        float inv0 = 1.0f / (float)max(len0, 1);
        float inv1 = 1.0f / (float)max(len1, 1);
        unsigned int p0 = (unsigned int)f2h(a0x * inv0) | ((unsigned int)f2h(a0y * inv0) << 16);
        unsigned int p1 = (unsigned int)f2h(a1x * inv1) | ((unsigned int)f2h(a1y * inv1) << 16);
        *(unsigned int*)&aggh[j0][dd] = p0;
        *(unsigned int*)&aggh[j1][dd] = p1;
    }
    __syncthreads();

    // ---- phase 3: GEMM1: U[16,256] = [xh | aggh] @ W3; wave owns 32 cols
    int wv = wid, q = lane >> 4, l15 = lane & 15;
    f32x4 acc[2];
    acc[0] = (f32x4){0.f, 0.f, 0.f, 0.f};
    acc[1] = (f32x4){0.f, 0.f, 0.f, 0.f};
    for (int kc = 0; kc < 8; ++kc) {
        f16x8 a;
        if (kc < 4) a = *(const f16x8*)&xh[(n0 + l15) * DIM + kc * 32 + q * 8];
        else        a = *(const f16x8*)&aggh[l15][(kc - 4) * 32 + q * 8];
#pragma unroll
        for (int nt = 0; nt < 2; ++nt) {
            f16x8 b = *(const f16x8*)&w3t[(wv * 32 + nt * 16 + l15) * 256 + kc * 32 + q * 8];
            acc[nt] = __builtin_amdgcn_mfma_f32_16x16x32_f16(a, b, acc[nt], 0, 0, 0);
        }
    }

    // bias + LN stats (intra-16-lane shfl, then cross-wave LDS sum)
    float b3v[2], gv[2], bvv[2];
#pragma unroll
    for (int nt = 0; nt < 2; ++nt) {
        int col = wv * 32 + nt * 16 + l15;
        b3v[nt] = b3[col]; gv[nt] = gamma[col]; bvv[nt] = beta[col];
    }
    {
        float s_[4], q_[4];
#pragma unroll
        for (int reg = 0; reg < 4; ++reg) {
            float su = 0.f, sq = 0.f;
#pragma unroll
            for (int nt = 0; nt < 2; ++nt) {
                float v = acc[nt][reg] + b3v[nt];
                acc[nt][reg] = v;
                su += v; sq += v * v;
            }
            s_[reg] = su; q_[reg] = sq;
        }
#pragma unroll
        for (int off = 1; off < 16; off <<= 1) {
#pragma unroll
            for (int reg = 0; reg < 4; ++reg) {
                s_[reg] += __shfl_xor(s_[reg], off, 64);
                q_[reg] += __shfl_xor(q_[reg], off, 64);
            }
        }
        if (l15 == 0) {
#pragma unroll
            for (int reg = 0; reg < 4; ++reg) {
                int r = q * 4 + reg;
                part_s[wv][r] = s_[reg];
                part_q[wv][r] = q_[reg];
            }
        }
    }
    __syncthreads();
    if (t < 16) {
        float st = 0.f, qt = 0.f;
#pragma unroll
        for (int w = 0; w < 8; ++w) { st += part_s[w][t]; qt += part_q[w][t]; }
        float mu = st * (1.0f / 256.0f);
        float var = qt * (1.0f / 256.0f) - mu * mu;
        tot_mu[t] = mu;
        tot_rs[t] = rsqrtf(var + LN_EPS);
    }
    __syncthreads();

    // LN + SiLU -> fp16 act in LDS (A-operand layout [m][k])
#pragma unroll
    for (int reg = 0; reg < 4; ++reg) {
        int r = q * 4 + reg;
        float mu = tot_mu[r], rs = tot_rs[r];
#pragma unroll
        for (int nt = 0; nt < 2; ++nt) {
            float un = (acc[nt][reg] - mu) * rs * gv[nt] + bvv[nt];
            float act = un / (1.0f + expf(-un));
            a_lds[r][wv * 32 + nt * 16 + l15] = f2h(act);
        }
    }
    __syncthreads();

    // GEMM2: out[16,128] = act @ W4; wave wv owns cols wv*16..+15
    f32x4 acc2 = (f32x4){0.f, 0.f, 0.f, 0.f};
    int col2 = wv * 16 + l15;
    for (int kc = 0; kc < 8; ++kc) {
        f16x8 a = *(const f16x8*)&a_lds[l15][kc * 32 + q * 8];
        f16x8 b = *(const f16x8*)&w4t[col2 * 256 + kc * 32 + q * 8];
        acc2 = __builtin_amdgcn_mfma_f32_16x16x32_f16(a, b, acc2, 0, 0, 0);
    }
    float b4v = b4[col2];
#pragma unroll
    for (int reg = 0; reg < 4; ++reg) {
        int node = n0 + q * 4 + reg;
        out[node * DIM + col2] = acc2[reg] + b4v;
    }
}

// ---------------------------------------------------------------------------
extern "C" void kernel_launch(void* const* d_in, const int* in_sizes, int n_in,
                              void* d_out, int out_size, void* d_ws, size_t ws_size,
                              hipStream_t stream) {
    const float* x     = (const float*)d_in[0];
    const float* h     = (const float*)d_in[1];
    const int*   ei    = (const int*)d_in[2];
    const float* W1    = (const float*)d_in[4];
    const float* b1    = (const float*)d_in[5];
    const float* W2    = (const float*)d_in[6];
    const float* b2    = (const float*)d_in[7];
    const float* W3    = (const float*)d_in[8];
    const float* b3    = (const float*)d_in[9];
    const float* gamma = (const float*)d_in[10];
    const float* beta  = (const float*)d_in[11];
    const float* W4    = (const float*)d_in[12];
    const float* b4    = (const float*)d_in[13];
    float* out = (float*)d_out;
    int nE = in_sizes[2] / 2;

    char* ws = (char*)d_ws;
    unsigned short* Tb   = (unsigned short*)ws; ws += (size_t)TK * DIM * 2;       // 1 MB
    unsigned short* w3t  = (unsigned short*)ws; ws += (size_t)HID * HID * 2;      // 128 KB
    unsigned short* w4t  = (unsigned short*)ws; ws += (size_t)DIM * HID * 2;      // 64 KB
    unsigned short* xh   = (unsigned short*)ws; ws += (size_t)BN_NODES * DIM * 2; // 4 MB
    unsigned char*  xq   = (unsigned char*)ws;  ws += (size_t)BN_NODES * DIM;     // 2 MB
    int* bin_cursor = (int*)ws;                 ws += (size_t)NBINS * 4;          // 4 KB
    unsigned int* staging = (unsigned int*)ws;  ws += (size_t)NBINS * CAPB * 4;   // 3 MB

    int binBlocks = (nE + EPB - 1) / EPB;
    hipMemsetAsync(bin_cursor, 0, (size_t)NBINS * 4, stream);
    prep_kernel<<<1632 + binBlocks, 256, 0, stream>>>(W1, b1, W2, b2, W3, W4, h, ei, x,
                                                      Tb, w3t, w4t, xh, xq,
                                                      bin_cursor, staging, nE);
    mega_kernel<<<NBINS, 512, 0, stream>>>(staging, bin_cursor, Tb, xq, xh,
                                           w3t, b3, gamma, beta, w4t, b4, out);
}